// Round 1
// 125.120 us; speedup vs baseline: 1.1187x; 1.1187x over previous
//
#include <hip/hip_runtime.h>

namespace {

constexpr int LMAX  = 10;
constexpr int NPART = 4;
// Greedy-balanced partition of l into 4 parts by inner-term count:
// P0{10,3}=42 terms, P1{9,4}=39, P2{8,5,1}=41, P3{7,6,2,0}=41
constexpr int PART_OF_L[LMAX + 1] = {3, 2, 3, 0, 1, 2, 3, 3, 2, 1, 0};
constexpr double PI_D = 3.14159265358979323846;

constexpr double dfact(int n) {
    double r = 1.0;
    for (int i = 2; i <= n; ++i) r *= (double)i;
    return r;
}

constexpr double csqrt(double x) {
    if (x <= 0.0) return 0.0;
    double g = x > 1.0 ? x : 1.0;
    for (int i = 0; i < 100; ++i) g = 0.5 * (g + x / g);
    return g;
}

constexpr double FACT[LMAX + 1] = {1., 1., 2., 6., 24., 120., 720., 5040., 40320., 362880., 3628800.};

// ---- per-part accumulator slot layout -------------------------------------
// For each l in the part (ascending): (l+1) real slots (m=0..l), then l imag
// slots (m=1..l).
constexpr int slot_base(int part, int l) {
    int c = 0;
    for (int ll = 0; ll < l; ++ll)
        if (PART_OF_L[ll] == part) c += 2 * ll + 1;
    return c;
}
constexpr int nacc_part(int part) {
    int c = 0;
    for (int l = 0; l <= LMAX; ++l)
        if (PART_OF_L[l] == part) c += 2 * l + 1;
    return c;
}
constexpr int part_lmax(int part) {
    int mx = 0;
    for (int l = 0; l <= LMAX; ++l)
        if (PART_OF_L[l] == part) mx = l;
    return mx;
}
constexpr int slot_r(int part, int l, int m) { return slot_base(part, l) + m; }
constexpr int slot_i(int part, int l, int m) { return slot_base(part, l) + (l + 1) + (m - 1); }

constexpr int MAXNA = 34;  // max nacc_part over parts (P3: 1+5+13+15 = 34)

// Horner coefficient for the collapsed imag sum: (-1)^q / ((q+m)! q! (l-m-2q)!)
constexpr float ci_coef(int l, int m, int q) {
    const double c = 1.0 / (FACT[q + m] * FACT[q] * FACT[l - m - 2 * q]);
    return (q & 1) ? (float)(-c) : (float)c;
}

struct Tables {
    int   map[NPART][MAXNA];
    float scl[NPART][MAXNA];
};

constexpr Tables make_tables() {
    Tables t{};
    for (int part = 0; part < NPART; ++part) {
        for (int l = 0; l <= LMAX; ++l) {
            if (PART_OF_L[l] != part) continue;
            for (int m = 0; m <= l; ++m) {
                const int k = slot_r(part, l, m);
                const double scale =
                    csqrt(dfact(l + m) * dfact(l - m)) * csqrt((2 * l + 1) / (4.0 * PI_D));
                // T==1 pairs (m >= l-1, m>=1): the single inner coefficient
                // c = 1/(m! (l-m)!) is folded into the output scale, so the
                // kernel does a bare table*wrl fma for those slots.
                const double fold = (m >= 1 && (l - m) <= 1) ? 1.0 / (dfact(m) * dfact(l - m)) : 1.0;
                if (m == 0) {
                    t.map[part][k] = l * l + l;
                    t.scl[part][k] = (float)(scale * fold);
                } else {
                    const double f = csqrt(2.0) * ((m & 1) ? -1.0 : 1.0);
                    t.map[part][k] = l * l + l + m;
                    t.scl[part][k] = (float)(f * scale * fold);
                }
            }
            for (int m = 1; m <= l; ++m) {
                const int k = slot_i(part, l, m);
                const double scale =
                    csqrt(dfact(l + m) * dfact(l - m)) * csqrt((2 * l + 1) / (4.0 * PI_D));
                const double f    = csqrt(2.0) * ((m & 1) ? -1.0 : 1.0);
                const double fold = ((l - m) <= 1) ? 1.0 / (dfact(m) * dfact(l - m)) : 1.0;
                t.map[part][k] = l * l + l - m;
                t.scl[part][k] = (float)(f * scale * fold);
            }
        }
    }
    return t;
}

__constant__ Tables c_tab = make_tables();

}  // namespace

// Algebra (exact in fp up to reassociation):
//   z1 = (-x/2, -y/2), z2 = -conj(z1)  =>  only one power table needed.
//   real term:  zreal = Re(z1^p)^2 - Im(z1^q)^2            = sr[p] - si[q]
//   imag term:  Im(z1^p)Re(z1^q) - Re(z1^p)Im(z1^q)
//             = Im(z1^p conj(z1^q)) = rho^q * Im(z1^m),  rho = |z1|^2
//   so the whole imag p-sum collapses to  zi[m] * Horner_q(+-c * rho^q):
//   1 fma/term instead of mul+fma+fma, and the zr[] table becomes a rolling
//   scalar.  T==1 (m >= l-1) pairs degenerate to a single fma with the
//   coefficient folded into the host-side scl table.
//
// 4-way l-split: each part keeps <=34 accumulators; __launch_bounds__(256,4)
// caps VGPR at 128 (4 waves/SIMD — above the measured 2.5), giving the
// allocator ~2x slack vs the previous 64-VGPR fit so it stops paying VALU
// rematerialization for occupancy we never achieved.
template <int PART>
__device__ __forceinline__ void sht_part(const float* __restrict__ pos,
                                         float* __restrict__ out, int n, int nblk) {
    constexpr int NA = nacc_part(PART);
    constexpr int PL = part_lmax(PART);

    float acc[NA];
#pragma unroll
    for (int k = 0; k < NA; ++k) acc[k] = 0.f;

    const int bid    = (int)(blockIdx.x >> 2);
    const int tid    = bid * 256 + (int)threadIdx.x;
    const int stride = nblk * 256;

    int   i = tid;
    float x = 0.f, y = 0.f, z0 = 0.f;
    if (i < n) {
        x  = pos[3 * i + 0];
        y  = pos[3 * i + 1];
        z0 = pos[3 * i + 2];
    }

    while (i < n) {
        // software-pipelined prefetch of the next point
        const int inext = i + stride;
        float     px = 0.f, py = 0.f, pz = 0.f;
        if (inext < n) {
            px = pos[3 * inext + 0];
            py = pos[3 * inext + 1];
            pz = pos[3 * inext + 2];
        }

        const float r2  = x * x + y * y + z0 * z0;
        const float nrm = sqrtf(r2);
        const float w0  = (nrm > 0.f) ? z0 : 0.f;  // x0 * mask

        const float ar = -0.5f * x, ai = -0.5f * y;
        const float rho = ar * ar + ai * ai;  // |z1|^2 = (x^2+y^2)/4

        // Power tables: zi[] (imag parts, needed for collapsed imag sums),
        // sr[p] = Re(z1^p)^2, si[p] = Im(z1^p)^2. Re(z1^p) is a rolling scalar.
        float zi[PL + 1], sr[PL + 1], si[PL + 1];
        zi[0] = 0.f;
        sr[0] = 1.f;
        si[0] = 0.f;
        float zrc = 1.f;
#pragma unroll
        for (int p = 1; p <= PL; ++p) {
            const float nzr = ar * zrc - ai * zi[p - 1];
            zi[p]           = ar * zi[p - 1] + ai * zrc;
            zrc             = nzr;
            sr[p]           = zrc * zrc;
            si[p]           = zi[p] * zi[p];
        }
        float rp[PL + 1];
        rp[0] = 1.f;
#pragma unroll
        for (int l = 1; l <= PL; ++l) rp[l] = rp[l - 1] * nrm;

#pragma unroll
        for (int l = 0; l <= LMAX; ++l) {
            if (PART_OF_L[l] != PART) continue;  // compile-time eliminated
            const float wrl = w0 * rp[l];
#pragma unroll
            for (int m = 0; m <= l; ++m) {
                const int Q = (l - m) >> 1;  // highest q in the sums
                if (m >= 1 && Q == 0) {
                    // single-term pair: coefficient folded into c_tab.scl
                    acc[slot_r(PART, l, m)] += sr[m] * wrl;
                    acc[slot_i(PART, l, m)] += zi[m] * wrl;
                } else {
                    float shr = 0.f;
#pragma unroll
                    for (int p = m; 2 * p <= l + m; ++p) {
                        const int   q  = p - m;
                        const float cr = (float)(1.0 / (FACT[p] * FACT[q] * FACT[l - 2 * p + m]));
                        shr += (sr[p] - si[q]) * cr;
                    }
                    acc[slot_r(PART, l, m)] += shr * wrl;
                    if (m >= 1) {
                        // shi = zi[m] * sum_q (+-c) rho^q   (Horner in rho)
                        float t = ci_coef(l, m, Q);
#pragma unroll
                        for (int q = Q - 1; q >= 0; --q) t = t * rho + ci_coef(l, m, q);
                        acc[slot_i(PART, l, m)] += (t * zi[m]) * wrl;
                    }
                }
            }
        }

        i  = inext;
        x  = px;
        y  = py;
        z0 = pz;
    }

    // Wave (64-lane) shuffle reduction, then cross-wave via LDS.
    __shared__ float red[4][NA];
    const int lane = threadIdx.x & 63;
    const int wav  = threadIdx.x >> 6;
#pragma unroll
    for (int k = 0; k < NA; ++k) {
        float v = acc[k];
#pragma unroll
        for (int off = 32; off > 0; off >>= 1) v += __shfl_down(v, off, 64);
        if (lane == 0) red[wav][k] = v;
    }
    __syncthreads();
    if ((int)threadIdx.x < NA) {
        const int   k = (int)threadIdx.x;
        const float v = red[0][k] + red[1][k] + red[2][k] + red[3][k];
        atomicAdd(&out[c_tab.map[PART][k]], v * c_tab.scl[PART][k]);
    }
}

__global__ __launch_bounds__(256, 4) void sht_kernel(const float* __restrict__ pos,
                                                     float* __restrict__ out, int n, int nblk) {
    // part = blockIdx & 3: under round-robin block->CU dispatch (stride 256,
    // 256 == 0 mod 4), all resident blocks on one CU share a part -> I$ locality.
    switch (blockIdx.x & 3) {
        case 0: sht_part<0>(pos, out, n, nblk); break;
        case 1: sht_part<1>(pos, out, n, nblk); break;
        case 2: sht_part<2>(pos, out, n, nblk); break;
        default: sht_part<3>(pos, out, n, nblk); break;
    }
}

extern "C" void kernel_launch(void* const* d_in, const int* in_sizes, int n_in,
                              void* d_out, int out_size, void* d_ws, size_t ws_size,
                              hipStream_t stream) {
    const float* pos = (const float*)d_in[0];
    float* out       = (float*)d_out;
    const int n      = in_sizes[0] / 3;  // (N,3) flat -> N points

    // d_out is poisoned before every launch; we accumulate via atomics.
    hipMemsetAsync(d_out, 0, (size_t)out_size * sizeof(float), stream);

    const int threads       = 256;
    const int nblk_per_part = 512;                    // ~15 pts/thread per part
    const int blocks        = NPART * nblk_per_part;  // 2048
    sht_kernel<<<blocks, threads, 0, stream>>>(pos, out, n, nblk_per_part);
}

// Round 2
// 123.507 us; speedup vs baseline: 1.1333x; 1.0131x over previous
//
#include <hip/hip_runtime.h>

namespace {

constexpr int LMAX  = 10;
constexpr int NPART = 2;
// Balanced 2-way partition of l by inner-term count:
// P0{10,7,6,3,2} = 82 terms / 61 slots, P1{9,8,5,4,1,0} = 79 terms / 60 slots
constexpr int PART_OF_L[LMAX + 1] = {1, 1, 0, 0, 1, 1, 0, 0, 1, 1, 0};
constexpr double PI_D = 3.14159265358979323846;

constexpr double dfact(int n) {
    double r = 1.0;
    for (int i = 2; i <= n; ++i) r *= (double)i;
    return r;
}

constexpr double csqrt(double x) {
    if (x <= 0.0) return 0.0;
    double g = x > 1.0 ? x : 1.0;
    for (int i = 0; i < 100; ++i) g = 0.5 * (g + x / g);
    return g;
}

constexpr double FACT[LMAX + 1] = {1., 1., 2., 6., 24., 120., 720., 5040., 40320., 362880., 3628800.};

// ---- per-part accumulator slot layout -------------------------------------
// For each l in the part (ascending): (l+1) real slots (m=0..l), then l imag
// slots (m=1..l).
constexpr int slot_base(int part, int l) {
    int c = 0;
    for (int ll = 0; ll < l; ++ll)
        if (PART_OF_L[ll] == part) c += 2 * ll + 1;
    return c;
}
constexpr int nacc_part(int part) {
    int c = 0;
    for (int l = 0; l <= LMAX; ++l)
        if (PART_OF_L[l] == part) c += 2 * l + 1;
    return c;
}
constexpr int part_lmax(int part) {
    int mx = 0;
    for (int l = 0; l <= LMAX; ++l)
        if (PART_OF_L[l] == part) mx = l;
    return mx;
}
constexpr int slot_r(int part, int l, int m) { return slot_base(part, l) + m; }
constexpr int slot_i(int part, int l, int m) { return slot_base(part, l) + (l + 1) + (m - 1); }

constexpr int MAXNA = 61;  // max nacc_part over parts (P0: 5+7+13+15+21 = 61)

// Horner coefficient for the collapsed imag sum: (-1)^q / ((q+m)! q! (l-m-2q)!)
constexpr float ci_coef(int l, int m, int q) {
    const double c = 1.0 / (FACT[q + m] * FACT[q] * FACT[l - m - 2 * q]);
    return (q & 1) ? (float)(-c) : (float)c;
}

struct Tables {
    int   map[NPART][MAXNA];
    float scl[NPART][MAXNA];
};

constexpr Tables make_tables() {
    Tables t{};
    for (int part = 0; part < NPART; ++part) {
        for (int l = 0; l <= LMAX; ++l) {
            if (PART_OF_L[l] != part) continue;
            for (int m = 0; m <= l; ++m) {
                const int k = slot_r(part, l, m);
                const double scale =
                    csqrt(dfact(l + m) * dfact(l - m)) * csqrt((2 * l + 1) / (4.0 * PI_D));
                // T==1 pairs (m >= l-1, m>=1): the single inner coefficient
                // c = 1/(m! (l-m)!) is folded into the output scale, so the
                // kernel does a bare table*wrl fma for those slots.
                const double fold = (m >= 1 && (l - m) <= 1) ? 1.0 / (dfact(m) * dfact(l - m)) : 1.0;
                if (m == 0) {
                    t.map[part][k] = l * l + l;
                    t.scl[part][k] = (float)(scale * fold);
                } else {
                    const double f = csqrt(2.0) * ((m & 1) ? -1.0 : 1.0);
                    t.map[part][k] = l * l + l + m;
                    t.scl[part][k] = (float)(f * scale * fold);
                }
            }
            for (int m = 1; m <= l; ++m) {
                const int k = slot_i(part, l, m);
                const double scale =
                    csqrt(dfact(l + m) * dfact(l - m)) * csqrt((2 * l + 1) / (4.0 * PI_D));
                const double f    = csqrt(2.0) * ((m & 1) ? -1.0 : 1.0);
                const double fold = ((l - m) <= 1) ? 1.0 / (dfact(m) * dfact(l - m)) : 1.0;
                t.map[part][k] = l * l + l - m;
                t.scl[part][k] = (float)(f * scale * fold);
            }
        }
    }
    return t;
}

__constant__ Tables c_tab = make_tables();

}  // namespace

// Algebra (exact in fp up to reassociation):
//   z1 = (-x/2, -y/2), z2 = -conj(z1)  =>  only one power table needed.
//   real term:  zreal = Re(z1^p)^2 - Im(z1^q)^2            = sr[p] - si[q]
//   imag term:  Im(z1^p z2^q) = (-1)^q rho^q * Im(z1^m),   rho = |z1|^2
//   so the whole imag p-sum collapses to  zi[m] * Horner_q(+-c * rho^q):
//   1 fma/term instead of mul+fma+fma, and the zr[] table becomes a rolling
//   scalar.  T==1 (m >= l-1) pairs degenerate to a single fma with the
//   coefficient folded into the host-side scl table.
//
// 2-way l-split (was 4-way): round-1 counters showed VGPR_Count=56 — the
// allocator has lots of headroom — while ~60% of per-part issue is the
// replicated preamble (power tables, rp chain, loads, loop control) that runs
// once per part per point.  Halving the part count halves that replication
// (~19% of total issue) and halves pos re-scan traffic.  61 accumulators +
// ~44 table regs fit under the __launch_bounds__(256,3) cap of 170 VGPR.
template <int PART>
__device__ __forceinline__ void sht_part(const float* __restrict__ pos,
                                         float* __restrict__ out, int n, int nblk) {
    constexpr int NA = nacc_part(PART);
    constexpr int PL = part_lmax(PART);

    float acc[NA];
#pragma unroll
    for (int k = 0; k < NA; ++k) acc[k] = 0.f;

    const int bid    = (int)(blockIdx.x >> 1);
    const int tid    = bid * 256 + (int)threadIdx.x;
    const int stride = nblk * 256;

    int   i = tid;
    float x = 0.f, y = 0.f, z0 = 0.f;
    if (i < n) {
        x  = pos[3 * i + 0];
        y  = pos[3 * i + 1];
        z0 = pos[3 * i + 2];
    }

    while (i < n) {
        // software-pipelined prefetch of the next point
        const int inext = i + stride;
        float     px = 0.f, py = 0.f, pz = 0.f;
        if (inext < n) {
            px = pos[3 * inext + 0];
            py = pos[3 * inext + 1];
            pz = pos[3 * inext + 2];
        }

        const float r2  = x * x + y * y + z0 * z0;
        const float nrm = sqrtf(r2);
        const float w0  = (nrm > 0.f) ? z0 : 0.f;  // x0 * mask

        const float ar = -0.5f * x, ai = -0.5f * y;
        const float rho = ar * ar + ai * ai;  // |z1|^2 = (x^2+y^2)/4

        // Power tables: zi[] (imag parts, needed for collapsed imag sums),
        // sr[p] = Re(z1^p)^2, si[p] = Im(z1^p)^2. Re(z1^p) is a rolling scalar.
        float zi[PL + 1], sr[PL + 1], si[PL + 1];
        zi[0] = 0.f;
        sr[0] = 1.f;
        si[0] = 0.f;
        float zrc = 1.f;
#pragma unroll
        for (int p = 1; p <= PL; ++p) {
            const float nzr = ar * zrc - ai * zi[p - 1];
            zi[p]           = ar * zi[p - 1] + ai * zrc;
            zrc             = nzr;
            sr[p]           = zrc * zrc;
            si[p]           = zi[p] * zi[p];
        }
        float rp[PL + 1];
        rp[0] = 1.f;
#pragma unroll
        for (int l = 1; l <= PL; ++l) rp[l] = rp[l - 1] * nrm;

#pragma unroll
        for (int l = 0; l <= LMAX; ++l) {
            if (PART_OF_L[l] != PART) continue;  // compile-time eliminated
            const float wrl = w0 * rp[l];
#pragma unroll
            for (int m = 0; m <= l; ++m) {
                const int Q = (l - m) >> 1;  // highest q in the sums
                if (m >= 1 && Q == 0) {
                    // single-term pair: coefficient folded into c_tab.scl
                    acc[slot_r(PART, l, m)] += sr[m] * wrl;
                    acc[slot_i(PART, l, m)] += zi[m] * wrl;
                } else {
                    float shr = 0.f;
#pragma unroll
                    for (int p = m; 2 * p <= l + m; ++p) {
                        const int   q  = p - m;
                        const float cr = (float)(1.0 / (FACT[p] * FACT[q] * FACT[l - 2 * p + m]));
                        shr += (sr[p] - si[q]) * cr;
                    }
                    acc[slot_r(PART, l, m)] += shr * wrl;
                    if (m >= 1) {
                        // shi = zi[m] * sum_q (+-c) rho^q   (Horner in rho)
                        float t = ci_coef(l, m, Q);
#pragma unroll
                        for (int q = Q - 1; q >= 0; --q) t = t * rho + ci_coef(l, m, q);
                        acc[slot_i(PART, l, m)] += (t * zi[m]) * wrl;
                    }
                }
            }
        }

        i  = inext;
        x  = px;
        y  = py;
        z0 = pz;
    }

    // Wave (64-lane) shuffle reduction, then cross-wave via LDS.
    __shared__ float red[4][NA];
    const int lane = threadIdx.x & 63;
    const int wav  = threadIdx.x >> 6;
#pragma unroll
    for (int k = 0; k < NA; ++k) {
        float v = acc[k];
#pragma unroll
        for (int off = 32; off > 0; off >>= 1) v += __shfl_down(v, off, 64);
        if (lane == 0) red[wav][k] = v;
    }
    __syncthreads();
    if ((int)threadIdx.x < NA) {
        const int   k = (int)threadIdx.x;
        const float v = red[0][k] + red[1][k] + red[2][k] + red[3][k];
        atomicAdd(&out[c_tab.map[PART][k]], v * c_tab.scl[PART][k]);
    }
}

__global__ __launch_bounds__(256, 3) void sht_kernel(const float* __restrict__ pos,
                                                     float* __restrict__ out, int n, int nblk) {
    // part = blockIdx & 1: under round-robin block->CU dispatch (stride 256,
    // 256 == 0 mod 2), all resident blocks on one CU share a part -> I$ locality.
    if (blockIdx.x & 1)
        sht_part<1>(pos, out, n, nblk);
    else
        sht_part<0>(pos, out, n, nblk);
}

extern "C" void kernel_launch(void* const* d_in, const int* in_sizes, int n_in,
                              void* d_out, int out_size, void* d_ws, size_t ws_size,
                              hipStream_t stream) {
    const float* pos = (const float*)d_in[0];
    float* out       = (float*)d_out;
    const int n      = in_sizes[0] / 3;  // (N,3) flat -> N points

    // d_out is poisoned before every launch; we accumulate via atomics.
    hipMemsetAsync(d_out, 0, (size_t)out_size * sizeof(float), stream);

    const int threads       = 256;
    // 384 blocks/part -> 768 total = 3 blocks/CU, matching the 3 waves/SIMD
    // residency target of __launch_bounds__(256,3); ~20 pts/thread keeps the
    // (now 61-slot) shuffle epilogue at ~5% of per-wave work.
    const int nblk_per_part = 384;
    const int blocks        = NPART * nblk_per_part;  // 768
    sht_kernel<<<blocks, threads, 0, stream>>>(pos, out, n, nblk_per_part);
}